// Round 3
// baseline (766.666 us; speedup 1.0000x reference)
//
#include <hip/hip_runtime.h>
#include <math.h>

#define NITEM 100
#define CDIM 512
#define HW 4096
#define KTOP 10

typedef __attribute__((ext_vector_type(8))) short bf16x8;
typedef __attribute__((ext_vector_type(4))) float f32x4;

__device__ inline unsigned short bf16u(float f) {
  unsigned int u = __float_as_uint(f);
  u += 0x7fffu + ((u >> 16) & 1u);     // RNE
  return (unsigned short)(u >> 16);
}

// ---- K1: fp32 logits GEMM + in-register top-10 + renorm -> dense bf16 W [N][112] ----
// 256 threads, 128 rows/block. Thread (trg=t>>4, tc=t&15): rows 8trg..8trg+7,
// items tc+16j (j=0..6). Row-group = 16 lanes sharing trg (width-16 shuffles).
__global__ __launch_bounds__(256, 4) void logits_topk(
    const float* __restrict__ x, const float* __restrict__ mp,
    unsigned short* __restrict__ Wd)
{
  __shared__ float qs[32 * 128];   // [kk][row]
  __shared__ float ms[32 * 128];   // [kk][item]

  const int t   = threadIdx.x;
  const int tc  = t & 15;
  const int trg = t >> 4;              // 0..15
  const int n0  = blockIdx.x * 128;
  const int b   = n0 >> 12;
  const int sp0 = n0 & (HW - 1);
  const float* xb = x + (size_t)b * CDIM * HW + sp0;

  const int item = t & 127;
  const int half = t >> 7;             // kk range 16*half..16*half+15
  const float* mrow = mp + (size_t)(item < NITEM ? item : 0) * CDIM + 16 * half;

  float acc[8][7];
  #pragma unroll
  for (int r = 0; r < 8; ++r)
    #pragma unroll
    for (int j = 0; j < 7; ++j) acc[r][j] = 0.f;

  for (int kt = 0; kt < 16; ++kt) {
    const int k0 = kt * 32;
    // issue global loads early (overlap with previous tile's tail + barrier)
    float4 qv[4];
    #pragma unroll
    for (int j = 0; j < 4; ++j) {
      int task = t + 256 * j;
      int kk = task >> 5, c4 = (task & 31) << 2;
      qv[j] = *(const float4*)(xb + (size_t)(k0 + kk) * HW + c4);
    }
    float4 mv4[4];
    #pragma unroll
    for (int u = 0; u < 4; ++u)
      mv4[u] = *(const float4*)(mrow + k0 + 4 * u);
    __syncthreads();
    #pragma unroll
    for (int j = 0; j < 4; ++j)
      *(float4*)(qs + 4 * (t + 256 * j)) = qv[j];
    #pragma unroll
    for (int u = 0; u < 4; ++u) {
      ms[(16 * half + 4 * u + 0) * 128 + item] = mv4[u].x;
      ms[(16 * half + 4 * u + 1) * 128 + item] = mv4[u].y;
      ms[(16 * half + 4 * u + 2) * 128 + item] = mv4[u].z;
      ms[(16 * half + 4 * u + 3) * 128 + item] = mv4[u].w;
    }
    __syncthreads();
    // fp32 register-tile GEMM: acc[8][7] += q[8] * m[7]
    #pragma unroll 2
    for (int kk = 0; kk < 32; ++kk) {
      const float* qr = qs + kk * 128 + 8 * trg;
      const float* mr = ms + kk * 128 + tc;
      float4 qa = *(const float4*)(qr);
      float4 qb = *(const float4*)(qr + 4);
      float mm[7] = {mr[0], mr[16], mr[32], mr[48], mr[64], mr[80], mr[96]};
      float qq[8] = {qa.x, qa.y, qa.z, qa.w, qb.x, qb.y, qb.z, qb.w};
      #pragma unroll
      for (int r = 0; r < 8; ++r)
        #pragma unroll
        for (int j = 0; j < 7; ++j)
          acc[r][j] = __builtin_fmaf(qq[r], mm[j], acc[r][j]);
    }
  }

  // ---- in-register softmax + top-10 + renorm per row (16-lane groups) ----
  const int baserow = n0 + 8 * trg;
  #pragma unroll 1
  for (int r = 0; r < 8; ++r) {
    float* la = acc[r];                 // destructive after Z is computed
    float att[KTOP]; int id[KTOP];
    float mx = 0.f, Z = 0.f;
    #pragma unroll 1
    for (int s = 0; s < KTOP; ++s) {
      float bv = -INFINITY; int bi = 0x7fffffff;
      #pragma unroll
      for (int j = 0; j < 7; ++j) {
        bool valid = (j < 6) || (tc < 4);       // item tc+16j < 100
        float v = valid ? la[j] : -INFINITY;
        if (v > bv) { bv = v; bi = tc + 16 * j; }  // ascending idx: > keeps lowest
      }
      #pragma unroll
      for (int d = 1; d < 16; d <<= 1) {
        float ov = __shfl_xor(bv, d, 16);
        int   oi = __shfl_xor(bi, d, 16);
        if (ov > bv || (ov == bv && oi < bi)) { bv = ov; bi = oi; }
      }
      if (s == 0) {                    // have global max: compute Z on unmasked values
        mx = bv;
        float zp = 0.f;
        #pragma unroll
        for (int j = 0; j < 7; ++j) {
          bool valid = (j < 6) || (tc < 4);
          zp += valid ? __expf(la[j] - mx) : 0.f;
        }
        #pragma unroll
        for (int d = 1; d < 16; d <<= 1) zp += __shfl_xor(zp, d, 16);
        Z = zp;
      }
      att[s] = bv; id[s] = bi;
      if ((bi & 15) == tc) la[bi >> 4] = -INFINITY;   // mask winner
    }
    float invZ = 1.f / Z;
    float p0 = invZ;                    // exp(att0-mx)=1
    float s2 = 0.f, w[KTOP];
    #pragma unroll
    for (int s = 0; s < KTOP; ++s) {
      float p = __expf(att[s] - mx) * invZ;
      float e = __expf(p - p0);
      w[s] = e; s2 += e;
    }
    float inv2 = 1.f / s2;
    // assemble W row in registers: lane tc owns items 8tc..8tc+7 (one float4)
    unsigned int zz[4] = {0u, 0u, 0u, 0u};
    #pragma unroll
    for (int s = 0; s < KTOP; ++s) {
      if ((id[s] >> 3) == tc) {
        int pos = id[s] & 7;
        unsigned int hw = (unsigned int)bf16u(w[s] * inv2);
        zz[pos >> 1] |= hw << (16 * (pos & 1));
      }
    }
    if (tc < 14) {
      uint4 o; o.x = zz[0]; o.y = zz[1]; o.z = zz[2]; o.w = zz[3];
      *(uint4*)(Wd + (size_t)(baserow + r) * 112 + 8 * tc) = o;
    }
  }
}

// ---- K2: out^T = mp^T(bf16) x W^T(bf16) via MFMA; tiles 128c x 128n, K=128 ----
__global__ __launch_bounds__(256, 2) void recon(
    const float* __restrict__ mp, const unsigned short* __restrict__ Wd,
    float* __restrict__ out)
{
  __shared__ unsigned short Ash[128 * 136];  // mp^T bf16 [c][k], k-stride 136
  __shared__ unsigned short Bsh[128 * 136];  // W bf16 [n][k]
  const int t  = threadIdx.x;
  const int ct = blockIdx.x & 3, nt = blockIdx.x >> 2;
  const int c0 = ct * 128, n0 = nt * 128;
  const int b  = n0 >> 12, sp0 = n0 & (HW - 1);

  // stage A: (k 0..99) x (c4 0..31) float4 tasks
  #pragma unroll
  for (int j = 0; j < 13; ++j) {
    int task = t + 256 * j;
    if (task < 3200) {
      int k = task >> 5, c4 = (task & 31) << 2;
      float4 v = *(const float4*)(mp + (size_t)k * CDIM + c0 + c4);
      Ash[(c4 + 0) * 136 + k] = bf16u(v.x);
      Ash[(c4 + 1) * 136 + k] = bf16u(v.y);
      Ash[(c4 + 2) * 136 + k] = bf16u(v.z);
      Ash[(c4 + 3) * 136 + k] = bf16u(v.w);
    }
  }
  // A zero-fill k=100..135
  {
    int c = t >> 1, hf = t & 1;
    unsigned int* A32 = (unsigned int*)Ash;
    #pragma unroll
    for (int j = 0; j < 9; ++j) { int k = 100 + 2 * (hf * 9 + j); A32[(c * 136 + k) >> 1] = 0u; }
  }
  // stage B rows (natural [n][112] bf16) + zero-fill k=112..135
  {
    int n = t >> 1, hf = t & 1;
    #pragma unroll
    for (int j = 0; j < 7; ++j) {
      int f = hf * 7 + j;
      *(bf16x8*)(Bsh + n * 136 + 8 * f) = *(const bf16x8*)(Wd + (size_t)(n0 + n) * 112 + 8 * f);
    }
    unsigned int* B32 = (unsigned int*)Bsh;
    #pragma unroll
    for (int j = 0; j < 6; ++j) { int k = 112 + 2 * (hf * 6 + j); B32[(n * 136 + k) >> 1] = 0u; }
  }
  __syncthreads();

  const int w = t >> 6, l = t & 63;
  const int arow = l & 15, kg = l >> 4;
  f32x4 acc[2][8];
  #pragma unroll
  for (int cr = 0; cr < 2; ++cr)
    #pragma unroll
    for (int n = 0; n < 8; ++n) acc[cr][n] = (f32x4){0.f, 0.f, 0.f, 0.f};

  #pragma unroll
  for (int ks = 0; ks < 4; ++ks) {
    bf16x8 a0 = *(bf16x8*)(Ash + ((2*w + 0) * 16 + arow) * 136 + ks * 32 + kg * 8);
    bf16x8 a1 = *(bf16x8*)(Ash + ((2*w + 1) * 16 + arow) * 136 + ks * 32 + kg * 8);
    #pragma unroll
    for (int nn = 0; nn < 8; ++nn) {
      bf16x8 bb = *(bf16x8*)(Bsh + (nn * 16 + arow) * 136 + ks * 32 + kg * 8);
      acc[0][nn] = __builtin_amdgcn_mfma_f32_16x16x32_bf16(a0, bb, acc[0][nn], 0, 0, 0);
      acc[1][nn] = __builtin_amdgcn_mfma_f32_16x16x32_bf16(a1, bb, acc[1][nn], 0, 0, 0);
    }
  }

  float* ob = out + (size_t)b * CDIM * HW + sp0;
  #pragma unroll
  for (int cr = 0; cr < 2; ++cr) {
    #pragma unroll
    for (int nn = 0; nn < 8; ++nn) {
      int ncol = nn * 16 + arow;
      #pragma unroll
      for (int j = 0; j < 4; ++j) {
        int cc = c0 + (2*w + cr) * 16 + kg * 4 + j;
        ob[(size_t)cc * HW + ncol] = acc[cr][nn][j];
      }
    }
  }
}

// ---- loss: mean |0.5 * off-diag gram| ----
__global__ void loss_partial(const float* __restrict__ mp, float* __restrict__ part)
{
  __shared__ float mi[CDIM];
  __shared__ float red[4];
  const int i = blockIdx.x;
  const int t = threadIdx.x;
  for (int k = t; k < CDIM; k += 256) mi[k] = mp[i * CDIM + k];
  __syncthreads();
  float v = 0.f;
  if (t < NITEM && t != i) {
    const float* mj = mp + t * CDIM;
    float d = 0.f;
    #pragma unroll 8
    for (int k = 0; k < CDIM; ++k) d += mi[k] * mj[k];
    v = fabsf(0.5f * d);
  }
  #pragma unroll
  for (int o = 32; o > 0; o >>= 1) v += __shfl_down(v, o, 64);
  if ((t & 63) == 0) red[t >> 6] = v;
  __syncthreads();
  if (t == 0) part[i] = red[0] + red[1] + red[2] + red[3];
}

__global__ void loss_final(const float* __restrict__ part, float* __restrict__ out_loss)
{
  if (threadIdx.x == 0) {
    float s = 0.f;
    for (int i = 0; i < NITEM; ++i) s += part[i];
    *out_loss = s / (float)(NITEM * NITEM);
  }
}

extern "C" void kernel_launch(void* const* d_in, const int* in_sizes, int n_in,
                              void* d_out, int out_size, void* d_ws, size_t ws_size,
                              hipStream_t stream) {
  const float* x  = (const float*)d_in[0];
  const float* mp = (const float*)d_in[1];
  float* out = (float*)d_out;
  unsigned short* Wd = (unsigned short*)d_ws;                    // 131072*112*2 = 29.36 MB
  float* part = (float*)((char*)d_ws + (size_t)131072 * 112 * 2);

  logits_topk<<<1024, 256, 0, stream>>>(x, mp, Wd);
  recon<<<4096, 256, 0, stream>>>(mp, Wd, out);
  loss_partial<<<NITEM, 256, 0, stream>>>(mp, part);
  loss_final<<<1, 64, 0, stream>>>(part, out + (out_size - 1));
}

// Round 5
// 386.895 us; speedup vs baseline: 1.9816x; 1.9816x over previous
//
#include <hip/hip_runtime.h>
#include <math.h>

#define NITEM 100
#define CDIM 512
#define HW 4096
#define KTOP 10

typedef __attribute__((ext_vector_type(8))) short bf16x8;
typedef __attribute__((ext_vector_type(4))) float f32x4;

__device__ inline unsigned short bf16u(float f) {
  unsigned int u = __float_as_uint(f);
  u += 0x7fffu + ((u >> 16) & 1u);     // RNE
  return (unsigned short)(u >> 16);
}

// ---- K1: fp32 logits GEMM + in-register top-10 + renorm -> dense bf16 W [N][112] ----
// 256 threads, 128 rows/block. Thread (trg=t>>4, tc=t&15): rows 8trg..8trg+7,
// items tc+16j (j=0..6). Row-group = 16 lanes sharing trg (width-16 shuffles).
// NOTE: every register-array index is compile-time constant (no scratch spill).
__global__ __launch_bounds__(256, 3) void logits_topk(
    const float* __restrict__ x, const float* __restrict__ mp,
    unsigned short* __restrict__ Wd)
{
  __shared__ float qs[32 * 128];   // [kk][row]
  __shared__ float ms[32 * 128];   // [kk][item]

  const int t   = threadIdx.x;
  const int tc  = t & 15;
  const int trg = t >> 4;              // 0..15
  const int n0  = blockIdx.x * 128;
  const int b   = n0 >> 12;
  const int sp0 = n0 & (HW - 1);
  const float* xb = x + (size_t)b * CDIM * HW + sp0;

  const int item = t & 127;
  const int half = t >> 7;             // kk range 16*half..16*half+15
  const float* mrow = mp + (size_t)(item < NITEM ? item : 0) * CDIM + 16 * half;

  float acc[8][7];
  #pragma unroll
  for (int r = 0; r < 8; ++r)
    #pragma unroll
    for (int j = 0; j < 7; ++j) acc[r][j] = 0.f;

  // prologue: load tile 0 into registers
  float4 qv[4], mv4[4];
  #pragma unroll
  for (int j = 0; j < 4; ++j) {
    int task = t + 256 * j;
    int kk = task >> 5, c4 = (task & 31) << 2;
    qv[j] = *(const float4*)(xb + (size_t)kk * HW + c4);
  }
  #pragma unroll
  for (int u = 0; u < 4; ++u) mv4[u] = *(const float4*)(mrow + 4 * u);

  #pragma unroll 1
  for (int kt = 0; kt < 16; ++kt) {
    // store staged registers -> LDS
    #pragma unroll
    for (int j = 0; j < 4; ++j)
      *(float4*)(qs + 4 * (t + 256 * j)) = qv[j];
    #pragma unroll
    for (int u = 0; u < 4; ++u) {
      ms[(16 * half + 4 * u + 0) * 128 + item] = mv4[u].x;
      ms[(16 * half + 4 * u + 1) * 128 + item] = mv4[u].y;
      ms[(16 * half + 4 * u + 2) * 128 + item] = mv4[u].z;
      ms[(16 * half + 4 * u + 3) * 128 + item] = mv4[u].w;
    }
    __syncthreads();
    // prefetch next tile (overlaps the FMA compute below)
    if (kt < 15) {
      const int k0n = (kt + 1) * 32;
      #pragma unroll
      for (int j = 0; j < 4; ++j) {
        int task = t + 256 * j;
        int kk = task >> 5, c4 = (task & 31) << 2;
        qv[j] = *(const float4*)(xb + (size_t)(k0n + kk) * HW + c4);
      }
      #pragma unroll
      for (int u = 0; u < 4; ++u) mv4[u] = *(const float4*)(mrow + k0n + 4 * u);
    }
    // fp32 register-tile GEMM: acc[8][7] += q[8] * m[7], sequential k
    #pragma unroll 2
    for (int kk = 0; kk < 32; ++kk) {
      const float* qr = qs + kk * 128 + 8 * trg;
      const float* mr = ms + kk * 128 + tc;
      float4 qa = *(const float4*)(qr);
      float4 qb = *(const float4*)(qr + 4);
      float mm[7] = {mr[0], mr[16], mr[32], mr[48], mr[64], mr[80], mr[96]};
      float qq[8] = {qa.x, qa.y, qa.z, qa.w, qb.x, qb.y, qb.z, qb.w};
      #pragma unroll
      for (int r = 0; r < 8; ++r)
        #pragma unroll
        for (int j = 0; j < 7; ++j)
          acc[r][j] = __builtin_fmaf(qq[r], mm[j], acc[r][j]);
    }
    __syncthreads();
  }

  // ---- in-register softmax + top-10 + renorm per row (16-lane groups) ----
  // FULLY unrolled: all acc/att/id/w indices compile-time constant.
  const int baserow = n0 + 8 * trg;
  #pragma unroll
  for (int r = 0; r < 8; ++r) {
    float attv[KTOP]; int id[KTOP];
    float mx = 0.f, Z = 0.f;
    #pragma unroll
    for (int s = 0; s < KTOP; ++s) {
      float bv = -INFINITY; int bi = 0x7fffffff;
      #pragma unroll
      for (int j = 0; j < 7; ++j) {
        bool valid = (j < 6) || (tc < 4);       // item tc+16j < 100
        float v = valid ? acc[r][j] : -INFINITY;
        if (v > bv) { bv = v; bi = tc + 16 * j; }  // ascending idx: > keeps lowest
      }
      #pragma unroll
      for (int d = 1; d < 16; d <<= 1) {
        float ov = __shfl_xor(bv, d, 16);
        int   oi = __shfl_xor(bi, d, 16);
        if (ov > bv || (ov == bv && oi < bi)) { bv = ov; bi = oi; }
      }
      if (s == 0) {                    // have global max: compute Z on unmasked values
        mx = bv;
        float zp = 0.f;
        #pragma unroll
        for (int j = 0; j < 7; ++j) {
          bool valid = (j < 6) || (tc < 4);
          zp += valid ? __expf(acc[r][j] - mx) : 0.f;
        }
        #pragma unroll
        for (int d = 1; d < 16; d <<= 1) zp += __shfl_xor(zp, d, 16);
        Z = zp;
      }
      attv[s] = bv; id[s] = bi;
      // mask winner (predicated, constant indices)
      #pragma unroll
      for (int j = 0; j < 7; ++j)
        if (bi == tc + 16 * j) acc[r][j] = -INFINITY;
    }
    float invZ = 1.f / Z;
    float p0 = invZ;                   // exp(attv0-mx)=1
    float s2 = 0.f, wv[KTOP];
    #pragma unroll
    for (int s = 0; s < KTOP; ++s) {
      float p = __expf(attv[s] - mx) * invZ;
      float e = __expf(p - p0);
      wv[s] = e; s2 += e;
    }
    float inv2 = 1.f / s2;
    unsigned short wb[KTOP];
    #pragma unroll
    for (int s = 0; s < KTOP; ++s) wb[s] = bf16u(wv[s] * inv2);
    // assemble W row: lane tc owns items 8tc..8tc+7 (one uint4), predicated selects
    unsigned int packed[4];
    #pragma unroll
    for (int q2 = 0; q2 < 4; ++q2) {
      unsigned int lo = 0u, hi = 0u;
      #pragma unroll
      for (int s = 0; s < KTOP; ++s) {
        lo = (id[s] == 8 * tc + 2 * q2)     ? (unsigned int)wb[s] : lo;
        hi = (id[s] == 8 * tc + 2 * q2 + 1) ? (unsigned int)wb[s] : hi;
      }
      packed[q2] = lo | (hi << 16);
    }
    if (tc < 14) {
      uint4 o; o.x = packed[0]; o.y = packed[1]; o.z = packed[2]; o.w = packed[3];
      *(uint4*)(Wd + (size_t)(baserow + r) * 112 + 8 * tc) = o;
    }
  }
}

// ---- K2: out^T = mp^T(bf16) x W^T(bf16) via MFMA; tiles 128c x 128n, K=128 ----
__global__ __launch_bounds__(256, 2) void recon(
    const float* __restrict__ mp, const unsigned short* __restrict__ Wd,
    float* __restrict__ out)
{
  __shared__ unsigned short Ash[128 * 136];  // mp^T bf16 [c][k], k-stride 136
  __shared__ unsigned short Bsh[128 * 136];  // W bf16 [n][k]
  const int t  = threadIdx.x;
  const int ct = blockIdx.x & 3, nt = blockIdx.x >> 2;
  const int c0 = ct * 128, n0 = nt * 128;
  const int b  = n0 >> 12, sp0 = n0 & (HW - 1);

  #pragma unroll
  for (int j = 0; j < 13; ++j) {
    int task = t + 256 * j;
    if (task < 3200) {
      int k = task >> 5, c4 = (task & 31) << 2;
      float4 v = *(const float4*)(mp + (size_t)k * CDIM + c0 + c4);
      Ash[(c4 + 0) * 136 + k] = bf16u(v.x);
      Ash[(c4 + 1) * 136 + k] = bf16u(v.y);
      Ash[(c4 + 2) * 136 + k] = bf16u(v.z);
      Ash[(c4 + 3) * 136 + k] = bf16u(v.w);
    }
  }
  {
    int c = t >> 1, hf = t & 1;
    unsigned int* A32 = (unsigned int*)Ash;
    #pragma unroll
    for (int j = 0; j < 9; ++j) { int k = 100 + 2 * (hf * 9 + j); A32[(c * 136 + k) >> 1] = 0u; }
  }
  {
    int n = t >> 1, hf = t & 1;
    #pragma unroll
    for (int j = 0; j < 7; ++j) {
      int f = hf * 7 + j;
      *(bf16x8*)(Bsh + n * 136 + 8 * f) = *(const bf16x8*)(Wd + (size_t)(n0 + n) * 112 + 8 * f);
    }
    unsigned int* B32 = (unsigned int*)Bsh;
    #pragma unroll
    for (int j = 0; j < 6; ++j) { int k = 112 + 2 * (hf * 6 + j); B32[(n * 136 + k) >> 1] = 0u; }
  }
  __syncthreads();

  const int w = t >> 6, l = t & 63;
  const int arow = l & 15, kg = l >> 4;
  f32x4 acc[2][8];
  #pragma unroll
  for (int cr = 0; cr < 2; ++cr)
    #pragma unroll
    for (int n = 0; n < 8; ++n) acc[cr][n] = (f32x4){0.f, 0.f, 0.f, 0.f};

  #pragma unroll
  for (int ks = 0; ks < 4; ++ks) {
    bf16x8 a0 = *(bf16x8*)(Ash + ((2 * w + 0) * 16 + arow) * 136 + ks * 32 + kg * 8);
    bf16x8 a1 = *(bf16x8*)(Ash + ((2 * w + 1) * 16 + arow) * 136 + ks * 32 + kg * 8);
    #pragma unroll
    for (int nn = 0; nn < 8; ++nn) {
      bf16x8 bb = *(bf16x8*)(Bsh + (nn * 16 + arow) * 136 + ks * 32 + kg * 8);
      acc[0][nn] = __builtin_amdgcn_mfma_f32_16x16x32_bf16(a0, bb, acc[0][nn], 0, 0, 0);
      acc[1][nn] = __builtin_amdgcn_mfma_f32_16x16x32_bf16(a1, bb, acc[1][nn], 0, 0, 0);
    }
  }

  float* ob = out + (size_t)b * CDIM * HW + sp0;
  #pragma unroll
  for (int cr = 0; cr < 2; ++cr) {
    #pragma unroll
    for (int nn = 0; nn < 8; ++nn) {
      int ncol = nn * 16 + arow;
      #pragma unroll
      for (int j = 0; j < 4; ++j) {
        int cc = c0 + (2 * w + cr) * 16 + kg * 4 + j;
        ob[(size_t)cc * HW + ncol] = acc[cr][nn][j];
      }
    }
  }
}

// ---- loss: mean |0.5 * off-diag gram| ----
__global__ void loss_partial(const float* __restrict__ mp, float* __restrict__ part)
{
  __shared__ float mi[CDIM];
  __shared__ float red[4];
  const int i = blockIdx.x;
  const int t = threadIdx.x;
  for (int k = t; k < CDIM; k += 256) mi[k] = mp[i * CDIM + k];
  __syncthreads();
  float v = 0.f;
  if (t < NITEM && t != i) {
    const float* mj = mp + t * CDIM;
    float d = 0.f;
    #pragma unroll 8
    for (int k = 0; k < CDIM; ++k) d += mi[k] * mj[k];
    v = fabsf(0.5f * d);
  }
  #pragma unroll
  for (int o = 32; o > 0; o >>= 1) v += __shfl_down(v, o, 64);
  if ((t & 63) == 0) red[t >> 6] = v;
  __syncthreads();
  if (t == 0) part[i] = red[0] + red[1] + red[2] + red[3];
}

__global__ void loss_final(const float* __restrict__ part, float* __restrict__ out_loss)
{
  if (threadIdx.x == 0) {
    float s = 0.f;
    for (int i = 0; i < NITEM; ++i) s += part[i];
    *out_loss = s / (float)(NITEM * NITEM);
  }
}

extern "C" void kernel_launch(void* const* d_in, const int* in_sizes, int n_in,
                              void* d_out, int out_size, void* d_ws, size_t ws_size,
                              hipStream_t stream) {
  const float* x  = (const float*)d_in[0];
  const float* mp = (const float*)d_in[1];
  float* out = (float*)d_out;
  unsigned short* Wd = (unsigned short*)d_ws;                    // 131072*112*2 = 29.36 MB
  float* part = (float*)((char*)d_ws + (size_t)131072 * 112 * 2);

  logits_topk<<<1024, 256, 0, stream>>>(x, mp, Wd);
  recon<<<4096, 256, 0, stream>>>(mp, Wd, out);
  loss_partial<<<NITEM, 256, 0, stream>>>(mp, part);
  loss_final<<<1, 64, 0, stream>>>(part, out + (out_size - 1));
}

// Round 6
// 374.364 us; speedup vs baseline: 2.0479x; 1.0335x over previous
//
#include <hip/hip_runtime.h>
#include <math.h>

#define NITEM 100
#define CDIM 512
#define HW 4096
#define KTOP 10

typedef __attribute__((ext_vector_type(8))) short bf16x8;
typedef __attribute__((ext_vector_type(4))) float f32x4;

__device__ inline unsigned short bf16u(float f) {
  unsigned int u = __float_as_uint(f);
  u += 0x7fffu + ((u >> 16) & 1u);     // RNE
  return (unsigned short)(u >> 16);
}

// ---- K1: fp32 logits GEMM + in-register top-10 + renorm -> dense bf16 W [N][112] ----
// 256 threads, 128 rows/block. Thread (trg=t>>4, tc=t&15): rows 8trg..8trg+7,
// items tc+16j (j=0..6). Row-group = 16 lanes sharing trg (width-16 shuffles).
// q staged via global_load_lds (double-buffered); m reg-staged (scatter writes).
// amdgpu_waves_per_eu(3,3): pin allocator at 3 waves/SIMD (~170 VGPR) -> no spill.
__global__ __launch_bounds__(256) __attribute__((amdgpu_waves_per_eu(3, 3)))
void logits_topk(
    const float* __restrict__ x, const float* __restrict__ mp,
    unsigned short* __restrict__ Wd)
{
  __shared__ float qs[2][32 * 128];   // [buf][kk][row]  2 x 16 KB
  __shared__ float ms[32 * 128];      // [kk][item]      16 KB

  const int t   = threadIdx.x;
  const int tc  = t & 15;
  const int trg = t >> 4;              // 0..15
  const int n0  = blockIdx.x * 128;
  const int b   = n0 >> 12;
  const int sp0 = n0 & (HW - 1);
  const float* xb = x + (size_t)b * CDIM * HW + sp0;

  const int w = t >> 6, l = t & 63;    // wave id, lane id
  const int item = t & 127;
  const int half = t >> 7;             // kk range 16*half..16*half+15
  const float* mrow = mp + (size_t)(item < NITEM ? item : 0) * CDIM + 16 * half;

  // q tile load: wave w covers kk = 8w..8w+7; per instr i: kk = 8w+2i+(l>>5), row = (l&31)*4
  auto issue_q = [&](int kt, int buf) {
    const int k0 = kt * 32;
    #pragma unroll
    for (int i = 0; i < 4; ++i) {
      const float* src = xb + (size_t)(k0 + 8 * w + 2 * i + (l >> 5)) * HW + (l & 31) * 4;
      float* dst = &qs[buf][(8 * w + 2 * i) * 128];        // wave-uniform base
      __builtin_amdgcn_global_load_lds(
          (const __attribute__((address_space(1))) void*)src,
          (__attribute__((address_space(3))) void*)dst, 16, 0, 0);
    }
  };

  float acc[8][7];
  #pragma unroll
  for (int r = 0; r < 8; ++r)
    #pragma unroll
    for (int j = 0; j < 7; ++j) acc[r][j] = 0.f;

  // prologue: tile 0
  issue_q(0, 0);
  float4 mv4[4];
  #pragma unroll
  for (int u = 0; u < 4; ++u) mv4[u] = *(const float4*)(mrow + 4 * u);

  int buf = 0;
  #pragma unroll 1
  for (int kt = 0; kt < 16; ++kt) {
    // store staged m registers -> LDS (scatter [kk][item])
    #pragma unroll
    for (int u = 0; u < 4; ++u) {
      ms[(16 * half + 4 * u + 0) * 128 + item] = mv4[u].x;
      ms[(16 * half + 4 * u + 1) * 128 + item] = mv4[u].y;
      ms[(16 * half + 4 * u + 2) * 128 + item] = mv4[u].z;
      ms[(16 * half + 4 * u + 3) * 128 + item] = mv4[u].w;
    }
    __syncthreads();                   // drains q(kt) vmcnt + m ds_writes
    // prefetch next tile (overlaps the FMA compute below)
    if (kt < 15) {
      issue_q(kt + 1, buf ^ 1);
      const int k0n = (kt + 1) * 32;
      #pragma unroll
      for (int u = 0; u < 4; ++u) mv4[u] = *(const float4*)(mrow + k0n + 4 * u);
    }
    // fp32 register-tile GEMM: acc[8][7] += q[8] * m[7], sequential k
    const float* qsb = qs[buf];
    #pragma unroll 2
    for (int kk = 0; kk < 32; ++kk) {
      const float* qr = qsb + kk * 128 + 8 * trg;
      const float* mr = ms + kk * 128 + tc;
      float4 qa = *(const float4*)(qr);
      float4 qb = *(const float4*)(qr + 4);
      float mm[7] = {mr[0], mr[16], mr[32], mr[48], mr[64], mr[80], mr[96]};
      float qq[8] = {qa.x, qa.y, qa.z, qa.w, qb.x, qb.y, qb.z, qb.w};
      #pragma unroll
      for (int r = 0; r < 8; ++r)
        #pragma unroll
        for (int j = 0; j < 7; ++j)
          acc[r][j] = __builtin_fmaf(qq[r], mm[j], acc[r][j]);
    }
    __syncthreads();                   // protect LDS overwrite next iter
    buf ^= 1;
  }

  // ---- in-register softmax + top-10 + renorm per row (16-lane groups) ----
  // FULLY unrolled: all acc/att/id/w indices compile-time constant.
  const int baserow = n0 + 8 * trg;
  #pragma unroll
  for (int r = 0; r < 8; ++r) {
    float attv[KTOP]; int id[KTOP];
    float mx = 0.f, Z = 0.f;
    #pragma unroll
    for (int s = 0; s < KTOP; ++s) {
      float bv = -INFINITY; int bi = 0x7fffffff;
      #pragma unroll
      for (int j = 0; j < 7; ++j) {
        bool valid = (j < 6) || (tc < 4);       // item tc+16j < 100
        float v = valid ? acc[r][j] : -INFINITY;
        if (v > bv) { bv = v; bi = tc + 16 * j; }  // ascending idx: > keeps lowest
      }
      #pragma unroll
      for (int d = 1; d < 16; d <<= 1) {
        float ov = __shfl_xor(bv, d, 16);
        int   oi = __shfl_xor(bi, d, 16);
        if (ov > bv || (ov == bv && oi < bi)) { bv = ov; bi = oi; }
      }
      if (s == 0) {                    // have global max: compute Z on unmasked values
        mx = bv;
        float zp = 0.f;
        #pragma unroll
        for (int j = 0; j < 7; ++j) {
          bool valid = (j < 6) || (tc < 4);
          zp += valid ? __expf(acc[r][j] - mx) : 0.f;
        }
        #pragma unroll
        for (int d = 1; d < 16; d <<= 1) zp += __shfl_xor(zp, d, 16);
        Z = zp;
      }
      attv[s] = bv; id[s] = bi;
      // mask winner (predicated, constant indices)
      #pragma unroll
      for (int j = 0; j < 7; ++j)
        if (bi == tc + 16 * j) acc[r][j] = -INFINITY;
    }
    float invZ = 1.f / Z;
    float p0 = invZ;                   // exp(attv0-mx)=1
    float s2 = 0.f, wv[KTOP];
    #pragma unroll
    for (int s = 0; s < KTOP; ++s) {
      float p = __expf(attv[s] - mx) * invZ;
      float e = __expf(p - p0);
      wv[s] = e; s2 += e;
    }
    float inv2 = 1.f / s2;
    unsigned short wb[KTOP];
    #pragma unroll
    for (int s = 0; s < KTOP; ++s) wb[s] = bf16u(wv[s] * inv2);
    // assemble W row: lane tc owns items 8tc..8tc+7 (one uint4), predicated selects
    unsigned int packed[4];
    #pragma unroll
    for (int q2 = 0; q2 < 4; ++q2) {
      unsigned int lo = 0u, hi = 0u;
      #pragma unroll
      for (int s = 0; s < KTOP; ++s) {
        lo = (id[s] == 8 * tc + 2 * q2)     ? (unsigned int)wb[s] : lo;
        hi = (id[s] == 8 * tc + 2 * q2 + 1) ? (unsigned int)wb[s] : hi;
      }
      packed[q2] = lo | (hi << 16);
    }
    if (tc < 14) {
      uint4 o; o.x = packed[0]; o.y = packed[1]; o.z = packed[2]; o.w = packed[3];
      *(uint4*)(Wd + (size_t)(baserow + r) * 112 + 8 * tc) = o;
    }
  }
}

// ---- K2: out^T = mp^T(bf16) x W^T(bf16) via MFMA; tiles 128c x 128n, K=128 ----
__global__ __launch_bounds__(256, 2) void recon(
    const float* __restrict__ mp, const unsigned short* __restrict__ Wd,
    float* __restrict__ out)
{
  __shared__ unsigned short Ash[128 * 136];  // mp^T bf16 [c][k], k-stride 136
  __shared__ unsigned short Bsh[128 * 136];  // W bf16 [n][k]
  const int t  = threadIdx.x;
  const int ct = blockIdx.x & 3, nt = blockIdx.x >> 2;
  const int c0 = ct * 128, n0 = nt * 128;
  const int b  = n0 >> 12, sp0 = n0 & (HW - 1);

  #pragma unroll
  for (int j = 0; j < 13; ++j) {
    int task = t + 256 * j;
    if (task < 3200) {
      int k = task >> 5, c4 = (task & 31) << 2;
      float4 v = *(const float4*)(mp + (size_t)k * CDIM + c0 + c4);
      Ash[(c4 + 0) * 136 + k] = bf16u(v.x);
      Ash[(c4 + 1) * 136 + k] = bf16u(v.y);
      Ash[(c4 + 2) * 136 + k] = bf16u(v.z);
      Ash[(c4 + 3) * 136 + k] = bf16u(v.w);
    }
  }
  {
    int c = t >> 1, hf = t & 1;
    unsigned int* A32 = (unsigned int*)Ash;
    #pragma unroll
    for (int j = 0; j < 9; ++j) { int k = 100 + 2 * (hf * 9 + j); A32[(c * 136 + k) >> 1] = 0u; }
  }
  {
    int n = t >> 1, hf = t & 1;
    #pragma unroll
    for (int j = 0; j < 7; ++j) {
      int f = hf * 7 + j;
      *(bf16x8*)(Bsh + n * 136 + 8 * f) = *(const bf16x8*)(Wd + (size_t)(n0 + n) * 112 + 8 * f);
    }
    unsigned int* B32 = (unsigned int*)Bsh;
    #pragma unroll
    for (int j = 0; j < 6; ++j) { int k = 112 + 2 * (hf * 6 + j); B32[(n * 136 + k) >> 1] = 0u; }
  }
  __syncthreads();

  const int w = t >> 6, l = t & 63;
  const int arow = l & 15, kg = l >> 4;
  f32x4 acc[2][8];
  #pragma unroll
  for (int cr = 0; cr < 2; ++cr)
    #pragma unroll
    for (int n = 0; n < 8; ++n) acc[cr][n] = (f32x4){0.f, 0.f, 0.f, 0.f};

  #pragma unroll
  for (int ks = 0; ks < 4; ++ks) {
    bf16x8 a0 = *(bf16x8*)(Ash + ((2 * w + 0) * 16 + arow) * 136 + ks * 32 + kg * 8);
    bf16x8 a1 = *(bf16x8*)(Ash + ((2 * w + 1) * 16 + arow) * 136 + ks * 32 + kg * 8);
    #pragma unroll
    for (int nn = 0; nn < 8; ++nn) {
      bf16x8 bb = *(bf16x8*)(Bsh + (nn * 16 + arow) * 136 + ks * 32 + kg * 8);
      acc[0][nn] = __builtin_amdgcn_mfma_f32_16x16x32_bf16(a0, bb, acc[0][nn], 0, 0, 0);
      acc[1][nn] = __builtin_amdgcn_mfma_f32_16x16x32_bf16(a1, bb, acc[1][nn], 0, 0, 0);
    }
  }

  float* ob = out + (size_t)b * CDIM * HW + sp0;
  #pragma unroll
  for (int cr = 0; cr < 2; ++cr) {
    #pragma unroll
    for (int nn = 0; nn < 8; ++nn) {
      int ncol = nn * 16 + arow;
      #pragma unroll
      for (int j = 0; j < 4; ++j) {
        int cc = c0 + (2 * w + cr) * 16 + kg * 4 + j;
        ob[(size_t)cc * HW + ncol] = acc[cr][nn][j];
      }
    }
  }
}

// ---- loss: mean |0.5 * off-diag gram| ----
__global__ void loss_partial(const float* __restrict__ mp, float* __restrict__ part)
{
  __shared__ float mi[CDIM];
  __shared__ float red[4];
  const int i = blockIdx.x;
  const int t = threadIdx.x;
  for (int k = t; k < CDIM; k += 256) mi[k] = mp[i * CDIM + k];
  __syncthreads();
  float v = 0.f;
  if (t < NITEM && t != i) {
    const float* mj = mp + t * CDIM;
    float d = 0.f;
    #pragma unroll 8
    for (int k = 0; k < CDIM; ++k) d += mi[k] * mj[k];
    v = fabsf(0.5f * d);
  }
  #pragma unroll
  for (int o = 32; o > 0; o >>= 1) v += __shfl_down(v, o, 64);
  if ((t & 63) == 0) red[t >> 6] = v;
  __syncthreads();
  if (t == 0) part[i] = red[0] + red[1] + red[2] + red[3];
}

__global__ void loss_final(const float* __restrict__ part, float* __restrict__ out_loss)
{
  if (threadIdx.x == 0) {
    float s = 0.f;
    for (int i = 0; i < NITEM; ++i) s += part[i];
    *out_loss = s / (float)(NITEM * NITEM);
  }
}

extern "C" void kernel_launch(void* const* d_in, const int* in_sizes, int n_in,
                              void* d_out, int out_size, void* d_ws, size_t ws_size,
                              hipStream_t stream) {
  const float* x  = (const float*)d_in[0];
  const float* mp = (const float*)d_in[1];
  float* out = (float*)d_out;
  unsigned short* Wd = (unsigned short*)d_ws;                    // 131072*112*2 = 29.36 MB
  float* part = (float*)((char*)d_ws + (size_t)131072 * 112 * 2);

  logits_topk<<<1024, 256, 0, stream>>>(x, mp, Wd);
  recon<<<4096, 256, 0, stream>>>(mp, Wd, out);
  loss_partial<<<NITEM, 256, 0, stream>>>(mp, part);
  loss_final<<<1, 64, 0, stream>>>(part, out + (out_size - 1));
}